// Round 6
// baseline (375.243 us; speedup 1.0000x reference)
//
#include <hip/hip_runtime.h>

#define N_NODES 50000
#define ELLW 48          // ELL width; P(deg>48) ~ 1e-15 for Poisson(16)

typedef unsigned int uint;
typedef unsigned short ushort;
typedef float floatx4 __attribute__((ext_vector_type(4)));
typedef short short8 __attribute__((ext_vector_type(8)));

__device__ inline ushort f2bf(float f) {
    uint u = __float_as_uint(f);
    return (ushort)((u + 0x7fffu + ((u >> 16) & 1u)) >> 16);
}
__device__ inline float bflo(uint u) { return __uint_as_float(u << 16); }
__device__ inline float bfhi(uint u) { return __uint_as_float(u & 0xffff0000u); }

// ---------------- K1 mega-kernel bodies ----------------

// swizzle [K,O] fp32 weight into MFMA B-frag order:
// Wz[((c*(O/16)+nb)*64 + lane)*8 + j] = W[c*32 + (lane>>4)*8 + j][nb*16 + (lane&15)]
__device__ inline void swz_body(const float* __restrict__ W, ushort* __restrict__ Wz,
                                int O, int t) {
    int lane = t & 63, cb = t >> 6;
    int NBm = O / 16;
    int c = cb / NBm, nb = cb % NBm;
    int quad = lane >> 4, l16 = lane & 15;
#pragma unroll
    for (int j = 0; j < 8; j++) {
        float v = W[(size_t)(c * 32 + quad * 8 + j) * O + nb * 16 + l16];
        Wz[(size_t)t * 8 + j] = f2bf(v);
    }
}

// GEMM1: x_p = relu(x @ Wp + bp); fp32 x, inline Wp swizzle (no deps in-dispatch)
__device__ void gemm1_body(int gb, const float* __restrict__ x,
                           const float* __restrict__ Wp, const float* __restrict__ bp,
                           ushort* __restrict__ feats, ushort* ldsA) {
    constexpr int LDA = 40;
    const int tid = threadIdx.x;
    const int wave = tid >> 6, lane = tid & 63;
    const int quad = lane >> 4, l16 = lane & 15;
    const int node0 = gb * 64;

    floatx4 acc[4];
#pragma unroll
    for (int nb = 0; nb < 4; nb++) acc[nb] = (floatx4){0.f, 0.f, 0.f, 0.f};

#pragma unroll
    for (int kk = 0; kk < 2; kk++) {
        const int k0 = kk * 32;
        __syncthreads();
        {
            int row = tid >> 2, seg = tid & 3;
            int node = node0 + row;
            float4 v0 = {0.f,0.f,0.f,0.f}, v1 = {0.f,0.f,0.f,0.f};
            if (node < N_NODES) {
                v0 = *(const float4*)&x[(size_t)node * 64 + k0 + seg * 8];
                v1 = *(const float4*)&x[(size_t)node * 64 + k0 + seg * 8 + 4];
            }
            ushort4 o0, o1;
            o0.x = f2bf(v0.x); o0.y = f2bf(v0.y); o0.z = f2bf(v0.z); o0.w = f2bf(v0.w);
            o1.x = f2bf(v1.x); o1.y = f2bf(v1.y); o1.z = f2bf(v1.z); o1.w = f2bf(v1.w);
            *(ushort4*)&ldsA[row * LDA + seg * 8] = o0;
            *(ushort4*)&ldsA[row * LDA + seg * 8 + 4] = o1;
        }
        __syncthreads();

        short8 a = *(const short8*)&ldsA[(wave * 16 + l16) * LDA + quad * 8];
#pragma unroll
        for (int nb = 0; nb < 4; nb++) {
            short8 bfrag;
#pragma unroll
            for (int j = 0; j < 8; j++)
                bfrag[j] = (short)f2bf(Wp[(size_t)(k0 + quad * 8 + j) * 64 + nb * 16 + l16]);
            acc[nb] = __builtin_amdgcn_mfma_f32_16x16x32_bf16(a, bfrag, acc[nb], 0, 0, 0);
        }
    }

#pragma unroll
    for (int nb = 0; nb < 4; nb++) {
        int ncol = nb * 16 + l16;
        float bv = bp[ncol];
#pragma unroll
        for (int r = 0; r < 4; r++) {
            int node = node0 + wave * 16 + quad * 4 + r;
            if (node >= N_NODES) continue;
            float v = fmaxf(acc[nb][r] + bv, 0.f);
            feats[(size_t)node * 256 + ncol] = f2bf(v);
        }
    }
}

// fused: [ELL fill | GEMM1 | x->bf16 convert | weight swizzles]
__global__ __launch_bounds__(256) void k1_mega(
    const int* __restrict__ src, const int* __restrict__ dst, int E,
    int* __restrict__ fillc, ushort* __restrict__ ell,
    const float* __restrict__ x, ushort* __restrict__ xb,
    const float* __restrict__ Wp, const float* __restrict__ bp, ushort* __restrict__ feats,
    const float* __restrict__ Wl1, ushort* __restrict__ zl1,
    const float* __restrict__ Wr1, ushort* __restrict__ zr1,
    const float* __restrict__ Wl2, ushort* __restrict__ zl2,
    const float* __restrict__ Wr2, ushort* __restrict__ zr2,
    const float* __restrict__ Wl3, ushort* __restrict__ zl3,
    const float* __restrict__ Wr3, ushort* __restrict__ zr3,
    int NF, int NG, int NC)
{
    __shared__ ushort ldsA[64 * 40];
    int b = blockIdx.x, tid = threadIdx.x;
    if (b < NF) {                       // ELL fill: 1 thread per edge
        int t = b * 256 + tid;
        if (t < E) {
            int d = dst[t], s = src[t];
            int p = atomicAdd(&fillc[d], 1);
            if (p < ELLW) ell[(size_t)d * ELLW + p] = (ushort)s;
        }
        return;
    }
    b -= NF;
    if (b < NG) { gemm1_body(b, x, Wp, bp, feats, ldsA); return; }
    b -= NG;
    if (b < NC) {                       // x -> bf16
        int t = b * 256 + tid;
        float4 v = ((const float4*)x)[t];
        ushort4 o;
        o.x = f2bf(v.x); o.y = f2bf(v.y); o.z = f2bf(v.z); o.w = f2bf(v.w);
        ((ushort4*)xb)[t] = o;
        return;
    }
    b -= NC;
    if      (b < 2)  swz_body(Wl1, zl1, 64,  (b - 0) * 256 + tid);
    else if (b < 4)  swz_body(Wr1, zr1, 64,  (b - 2) * 256 + tid);
    else if (b < 12) swz_body(Wl2, zl2, 128, (b - 4) * 256 + tid);
    else if (b < 20) swz_body(Wr2, zr2, 128, (b - 12) * 256 + tid);
    else if (b < 36) swz_body(Wl3, zl3, 128, (b - 20) * 256 + tid);
    else             swz_body(Wr3, zr3, 128, (b - 36) * 256 + tid);
}

// ---------------- fused gather + GEMM layers ----------------
// Block = 64 nodes, 4 waves. Gather phase: wave w computes mean-aggregated
// features for rows 16w..16w+15 directly into the LDS A-tile (half-wave edge
// split, shfl_xor combine). Then MFMA phase reads A-frags from LDS.

// F1: h1 = relu(mean(xb) @ Wl1 + xb @ Wr1 + bl1) -> feats[:,64:128]
__global__ __launch_bounds__(256) void fused_h1_k(
    const int* __restrict__ fillc, const ushort* __restrict__ ell,
    const ushort* __restrict__ xb,
    const ushort* __restrict__ zl1, const ushort* __restrict__ zr1,
    const float* __restrict__ bl1, ushort* __restrict__ feats)
{
    constexpr int LDG = 72;  // 64 cols + 8 pad (144 B stride, 16B-aligned)
    __shared__ ushort ldsG[64 * LDG];
    __shared__ ushort ldsR[64 * LDG];
    const int tid = threadIdx.x;
    const int wave = tid >> 6, lane = tid & 63;
    const int quad = lane >> 4, l16 = lane & 15;
    const int half = lane >> 5, c = lane & 31;
    const int node0 = blockIdx.x * 64;

    // stage root tile: xb rows node0..node0+63 (64 x 64 bf16, 512 16B segs)
#pragma unroll
    for (int it = 0; it < 2; it++) {
        int s = tid + it * 256;
        int row = s >> 3, seg = s & 7;
        int node = node0 + row;
        uint4 v = {0u,0u,0u,0u};
        if (node < N_NODES) v = *(const uint4*)&xb[(size_t)node * 64 + seg * 8];
        *(uint4*)&ldsR[row * LDG + seg * 8] = v;
    }

    // gather mean(xb) for this block's rows
    for (int mi = 0; mi < 16; mi++) {
        int row = wave * 16 + mi;
        int node = node0 + row;
        if (node >= N_NODES) break;
        int n = fillc[node]; int nc = (n > ELLW) ? ELLW : n;
        const ushort* base = ell + (size_t)node * ELLW;
        float a0 = 0.f, a1 = 0.f;
        int i = half;
        for (; i + 2 < nc; i += 4) {
            int s0 = base[i], s1 = base[i + 2];
            uint u0 = *(const uint*)&xb[(size_t)s0 * 64 + 2 * c];
            uint u1 = *(const uint*)&xb[(size_t)s1 * 64 + 2 * c];
            a0 += bflo(u0) + bflo(u1);
            a1 += bfhi(u0) + bfhi(u1);
        }
        if (i < nc) {
            uint u0 = *(const uint*)&xb[(size_t)base[i] * 64 + 2 * c];
            a0 += bflo(u0); a1 += bfhi(u0);
        }
        a0 += __shfl_xor(a0, 32);
        a1 += __shfl_xor(a1, 32);
        if (half == 0) {
            float iv = 1.0f / fmaxf((float)n, 1.0f);
            *(uint*)&ldsG[row * LDG + 2 * c] = (uint)f2bf(a0 * iv) | ((uint)f2bf(a1 * iv) << 16);
        }
    }
    __syncthreads();

    floatx4 acc[4];
#pragma unroll
    for (int nb = 0; nb < 4; nb++) acc[nb] = (floatx4){0.f, 0.f, 0.f, 0.f};

#pragma unroll
    for (int kc = 0; kc < 2; kc++) {
        short8 ag = *(const short8*)&ldsG[(wave * 16 + l16) * LDG + kc * 32 + quad * 8];
        const short8* bzl = (const short8*)zl1 + (size_t)kc * 4 * 64;
#pragma unroll
        for (int nb = 0; nb < 4; nb++)
            acc[nb] = __builtin_amdgcn_mfma_f32_16x16x32_bf16(ag, bzl[nb * 64 + lane], acc[nb], 0, 0, 0);
        short8 ar = *(const short8*)&ldsR[(wave * 16 + l16) * LDG + kc * 32 + quad * 8];
        const short8* bzr = (const short8*)zr1 + (size_t)kc * 4 * 64;
#pragma unroll
        for (int nb = 0; nb < 4; nb++)
            acc[nb] = __builtin_amdgcn_mfma_f32_16x16x32_bf16(ar, bzr[nb * 64 + lane], acc[nb], 0, 0, 0);
    }

#pragma unroll
    for (int nb = 0; nb < 4; nb++) {
        int ncol = nb * 16 + l16;
        float bv = bl1[ncol];
#pragma unroll
        for (int r = 0; r < 4; r++) {
            int node = node0 + wave * 16 + quad * 4 + r;
            if (node >= N_NODES) continue;
            feats[(size_t)node * 256 + 64 + ncol] = f2bf(fmaxf(acc[nb][r] + bv, 0.f));
        }
    }
}

// F2: h2 = relu(mean(feats[:,0:128]) @ Wl2 + feats[:,0:128] @ Wr2 + bl2)
//     -> feats[:,128:256]; gathered means also spilled to aggA[N,128] for F3.
__global__ __launch_bounds__(256) void fused_h2_k(
    const int* __restrict__ fillc, const ushort* __restrict__ ell,
    ushort* __restrict__ feats, ushort* __restrict__ aggA,
    const ushort* __restrict__ zl2, const ushort* __restrict__ zr2,
    const float* __restrict__ bl2)
{
    constexpr int LDG = 136;  // 128 cols + 8 pad (272 B stride)
    __shared__ ushort ldsG[64 * LDG];
    __shared__ ushort ldsR[64 * LDG];
    const int tid = threadIdx.x;
    const int wave = tid >> 6, lane = tid & 63;
    const int quad = lane >> 4, l16 = lane & 15;
    const int half = lane >> 5, c = lane & 31;
    const int node0 = blockIdx.x * 64;

    // stage root tile: feats rows, cols 0:128 (64 x 128 bf16, 1024 16B segs)
#pragma unroll
    for (int it = 0; it < 4; it++) {
        int s = tid + it * 256;
        int row = s >> 4, seg = s & 15;
        int node = node0 + row;
        uint4 v = {0u,0u,0u,0u};
        if (node < N_NODES) v = *(const uint4*)&feats[(size_t)node * 256 + seg * 8];
        *(uint4*)&ldsR[row * LDG + seg * 8] = v;
    }

    // gather mean(feats[:,0:128])
    for (int mi = 0; mi < 16; mi++) {
        int row = wave * 16 + mi;
        int node = node0 + row;
        if (node >= N_NODES) break;
        int n = fillc[node]; int nc = (n > ELLW) ? ELLW : n;
        const ushort* base = ell + (size_t)node * ELLW;
        float a0 = 0.f, a1 = 0.f, a2 = 0.f, a3 = 0.f;
        int i = half;
        for (; i + 2 < nc; i += 4) {
            int s0 = base[i], s1 = base[i + 2];
            uint2 u0 = *(const uint2*)&feats[(size_t)s0 * 256 + 4 * c];
            uint2 u1 = *(const uint2*)&feats[(size_t)s1 * 256 + 4 * c];
            a0 += bflo(u0.x) + bflo(u1.x);
            a1 += bfhi(u0.x) + bfhi(u1.x);
            a2 += bflo(u0.y) + bflo(u1.y);
            a3 += bfhi(u0.y) + bfhi(u1.y);
        }
        if (i < nc) {
            uint2 u0 = *(const uint2*)&feats[(size_t)base[i] * 256 + 4 * c];
            a0 += bflo(u0.x); a1 += bfhi(u0.x);
            a2 += bflo(u0.y); a3 += bfhi(u0.y);
        }
        a0 += __shfl_xor(a0, 32);
        a1 += __shfl_xor(a1, 32);
        a2 += __shfl_xor(a2, 32);
        a3 += __shfl_xor(a3, 32);
        if (half == 0) {
            float iv = 1.0f / fmaxf((float)n, 1.0f);
            uint2 r;
            r.x = (uint)f2bf(a0 * iv) | ((uint)f2bf(a1 * iv) << 16);
            r.y = (uint)f2bf(a2 * iv) | ((uint)f2bf(a3 * iv) << 16);
            *(uint2*)&ldsG[row * LDG + 4 * c] = r;
            *(uint2*)&aggA[(size_t)node * 128 + 4 * c] = r;   // spill for F3
        }
    }
    __syncthreads();

    floatx4 acc[8];
#pragma unroll
    for (int nb = 0; nb < 8; nb++) acc[nb] = (floatx4){0.f, 0.f, 0.f, 0.f};

#pragma unroll
    for (int kc = 0; kc < 4; kc++) {
        short8 ag = *(const short8*)&ldsG[(wave * 16 + l16) * LDG + kc * 32 + quad * 8];
        const short8* bzl = (const short8*)zl2 + (size_t)kc * 8 * 64;
#pragma unroll
        for (int nb = 0; nb < 8; nb++)
            acc[nb] = __builtin_amdgcn_mfma_f32_16x16x32_bf16(ag, bzl[nb * 64 + lane], acc[nb], 0, 0, 0);
        short8 ar = *(const short8*)&ldsR[(wave * 16 + l16) * LDG + kc * 32 + quad * 8];
        const short8* bzr = (const short8*)zr2 + (size_t)kc * 8 * 64;
#pragma unroll
        for (int nb = 0; nb < 8; nb++)
            acc[nb] = __builtin_amdgcn_mfma_f32_16x16x32_bf16(ar, bzr[nb * 64 + lane], acc[nb], 0, 0, 0);
    }

#pragma unroll
    for (int nb = 0; nb < 8; nb++) {
        int ncol = nb * 16 + l16;
        float bv = bl2[ncol];
#pragma unroll
        for (int r = 0; r < 4; r++) {
            int node = node0 + wave * 16 + quad * 4 + r;
            if (node >= N_NODES) continue;
            feats[(size_t)node * 256 + 128 + ncol] = f2bf(fmaxf(acc[nb][r] + bv, 0.f));
        }
    }
}

// F3: h3 = relu([aggA | mean(h2)] @ Wl3 + feats[:,0:256] @ Wr3 + bl3) -> d_out fp32
__global__ __launch_bounds__(256) void fused_h3_k(
    const int* __restrict__ fillc, const ushort* __restrict__ ell,
    const ushort* __restrict__ feats, const ushort* __restrict__ aggA,
    const ushort* __restrict__ zl3, const ushort* __restrict__ zr3,
    const float* __restrict__ bl3, float* __restrict__ out)
{
    constexpr int LDG = 136, LDS_ = 40;
    __shared__ ushort ldsG[64 * LDG];   // gathered mean(h2): agg k-chunks 4..7
    __shared__ ushort stg[64 * LDS_];   // 32-col staging for global operands
    const int tid = threadIdx.x;
    const int wave = tid >> 6, lane = tid & 63;
    const int quad = lane >> 4, l16 = lane & 15;
    const int half = lane >> 5, c = lane & 31;
    const int node0 = blockIdx.x * 64;

    // gather mean(feats[:,128:256]) -> ldsG
    for (int mi = 0; mi < 16; mi++) {
        int row = wave * 16 + mi;
        int node = node0 + row;
        if (node >= N_NODES) break;
        int n = fillc[node]; int nc = (n > ELLW) ? ELLW : n;
        const ushort* base = ell + (size_t)node * ELLW;
        float a0 = 0.f, a1 = 0.f, a2 = 0.f, a3 = 0.f;
        int i = half;
        for (; i + 2 < nc; i += 4) {
            int s0 = base[i], s1 = base[i + 2];
            uint2 u0 = *(const uint2*)&feats[(size_t)s0 * 256 + 128 + 4 * c];
            uint2 u1 = *(const uint2*)&feats[(size_t)s1 * 256 + 128 + 4 * c];
            a0 += bflo(u0.x) + bflo(u1.x);
            a1 += bfhi(u0.x) + bfhi(u1.x);
            a2 += bflo(u0.y) + bflo(u1.y);
            a3 += bfhi(u0.y) + bfhi(u1.y);
        }
        if (i < nc) {
            uint2 u0 = *(const uint2*)&feats[(size_t)base[i] * 256 + 128 + 4 * c];
            a0 += bflo(u0.x); a1 += bfhi(u0.x);
            a2 += bflo(u0.y); a3 += bfhi(u0.y);
        }
        a0 += __shfl_xor(a0, 32);
        a1 += __shfl_xor(a1, 32);
        a2 += __shfl_xor(a2, 32);
        a3 += __shfl_xor(a3, 32);
        if (half == 0) {
            float iv = 1.0f / fmaxf((float)n, 1.0f);
            uint2 r;
            r.x = (uint)f2bf(a0 * iv) | ((uint)f2bf(a1 * iv) << 16);
            r.y = (uint)f2bf(a2 * iv) | ((uint)f2bf(a3 * iv) << 16);
            *(uint2*)&ldsG[row * LDG + 4 * c] = r;
        }
    }

    floatx4 acc[8];
#pragma unroll
    for (int nb = 0; nb < 8; nb++) acc[nb] = (floatx4){0.f, 0.f, 0.f, 0.f};

    // agg chunks 0..3: aggA[N,128] via staging
#pragma unroll 1
    for (int kc = 0; kc < 4; kc++) {
        __syncthreads();
        {
            int row = tid >> 2, seg = tid & 3;
            int node = node0 + row;
            uint4 v = {0u,0u,0u,0u};
            if (node < N_NODES) v = *(const uint4*)&aggA[(size_t)node * 128 + kc * 32 + seg * 8];
            *(uint4*)&stg[row * LDS_ + seg * 8] = v;
        }
        __syncthreads();
        short8 a = *(const short8*)&stg[(wave * 16 + l16) * LDS_ + quad * 8];
        const short8* bz = (const short8*)zl3 + (size_t)kc * 8 * 64;
#pragma unroll
        for (int nb = 0; nb < 8; nb++)
            acc[nb] = __builtin_amdgcn_mfma_f32_16x16x32_bf16(a, bz[nb * 64 + lane], acc[nb], 0, 0, 0);
    }
    // agg chunks 4..7: gathered h2 means in ldsG (no staging)
#pragma unroll
    for (int kc = 0; kc < 4; kc++) {
        short8 a = *(const short8*)&ldsG[(wave * 16 + l16) * LDG + kc * 32 + quad * 8];
        const short8* bz = (const short8*)zl3 + (size_t)(4 + kc) * 8 * 64;
#pragma unroll
        for (int nb = 0; nb < 8; nb++)
            acc[nb] = __builtin_amdgcn_mfma_f32_16x16x32_bf16(a, bz[nb * 64 + lane], acc[nb], 0, 0, 0);
    }
    // root chunks 0..7: feats[:,0:256] via staging
#pragma unroll 1
    for (int kc = 0; kc < 8; kc++) {
        __syncthreads();
        {
            int row = tid >> 2, seg = tid & 3;
            int node = node0 + row;
            uint4 v = {0u,0u,0u,0u};
            if (node < N_NODES) v = *(const uint4*)&feats[(size_t)node * 256 + kc * 32 + seg * 8];
            *(uint4*)&stg[row * LDS_ + seg * 8] = v;
        }
        __syncthreads();
        short8 a = *(const short8*)&stg[(wave * 16 + l16) * LDS_ + quad * 8];
        const short8* bz = (const short8*)zr3 + (size_t)kc * 8 * 64;
#pragma unroll
        for (int nb = 0; nb < 8; nb++)
            acc[nb] = __builtin_amdgcn_mfma_f32_16x16x32_bf16(a, bz[nb * 64 + lane], acc[nb], 0, 0, 0);
    }

#pragma unroll
    for (int nb = 0; nb < 8; nb++) {
        int ncol = nb * 16 + l16;
        float bv = bl3[ncol];
#pragma unroll
        for (int r = 0; r < 4; r++) {
            int node = node0 + wave * 16 + quad * 4 + r;
            if (node >= N_NODES) continue;
            out[(size_t)node * 128 + ncol] = fmaxf(acc[nb][r] + bv, 0.f);
        }
    }
}

// ---------------- launch ----------------

extern "C" void kernel_launch(void* const* d_in, const int* in_sizes, int n_in,
                              void* d_out, int out_size, void* d_ws, size_t ws_size,
                              hipStream_t stream) {
    const float* x   = (const float*)d_in[0];
    const int*   ei  = (const int*)d_in[1];
    const float* Wp  = (const float*)d_in[2];
    const float* bp  = (const float*)d_in[3];
    const float* Wl1 = (const float*)d_in[4];
    const float* bl1 = (const float*)d_in[5];
    const float* Wr1 = (const float*)d_in[6];
    const float* Wl2 = (const float*)d_in[7];
    const float* bl2 = (const float*)d_in[8];
    const float* Wr2 = (const float*)d_in[9];
    const float* Wl3 = (const float*)d_in[10];
    const float* bl3 = (const float*)d_in[11];
    const float* Wr3 = (const float*)d_in[12];

    const int E = in_sizes[1] / 2;
    const int N = N_NODES;
    const int* src = ei;
    const int* dst = ei + E;

    // ---- workspace carve-up (all offsets 16B-aligned) ----
    char* p = (char*)d_ws;
    ushort* xb    = (ushort*)p;  p += (size_t)N * 64 * 2;
    ushort* feats = (ushort*)p;  p += (size_t)N * 256 * 2;
    ushort* aggA  = (ushort*)p;  p += (size_t)N * 128 * 2;
    int* fillc    = (int*)p;     p += (size_t)N * 4;
    ushort* ell   = (ushort*)p;  p += (size_t)N * ELLW * 2;
    ushort* zl1   = (ushort*)p;  p += 64 * 64 * 2;
    ushort* zr1   = (ushort*)p;  p += 64 * 64 * 2;
    ushort* zl2   = (ushort*)p;  p += 128 * 128 * 2;
    ushort* zr2   = (ushort*)p;  p += 128 * 128 * 2;
    ushort* zl3   = (ushort*)p;  p += 256 * 128 * 2;
    ushort* zr3   = (ushort*)p;  p += 256 * 128 * 2;

    hipMemsetAsync(fillc, 0, (size_t)N * sizeof(int), stream);

    const int NF = (E + 255) / 256;       // 3125 fill blocks
    const int NG = (N + 63) / 64;         // 782 gemm blocks
    const int NC = (N * 64 / 4) / 256;    // 3125 cvt blocks

    // K1: fill + GEMM1(x_p) + cvt + swz
    k1_mega<<<NF + NG + NC + 52, 256, 0, stream>>>(
        src, dst, E, fillc, ell, x, xb, Wp, bp, feats,
        Wl1, zl1, Wr1, zr1, Wl2, zl2, Wr2, zr2, Wl3, zl3, Wr3, zr3,
        NF, NG, NC);

    // F1: gather64(xb) + h1 -> feats[:,64:128]
    fused_h1_k<<<NG, 256, 0, stream>>>(fillc, ell, xb, zl1, zr1, bl1, feats);

    // F2: gather128(feats[:,0:128]) + h2 -> feats[:,128:256]; spills aggA
    fused_h2_k<<<NG, 256, 0, stream>>>(fillc, ell, feats, aggA, zl2, zr2, bl2);

    // F3: gather128(h2) + [aggA | gathered] @ Wl3 + feats @ Wr3 -> d_out
    fused_h3_k<<<NG, 256, 0, stream>>>(fillc, ell, feats, aggA, zl3, zr3, bl3, (float*)d_out);
}

// Round 7
// 291.444 us; speedup vs baseline: 1.2875x; 1.2875x over previous
//
#include <hip/hip_runtime.h>

#define N_NODES 50000
#define ELLW 48          // ELL width; P(deg>48) ~ 1e-15 for Poisson(16)

typedef unsigned int uint;
typedef unsigned short ushort;
typedef float floatx4 __attribute__((ext_vector_type(4)));
typedef short short8 __attribute__((ext_vector_type(8)));

__device__ inline ushort f2bf(float f) {
    uint u = __float_as_uint(f);
    return (ushort)((u + 0x7fffu + ((u >> 16) & 1u)) >> 16);
}
__device__ inline float bflo(uint u) { return __uint_as_float(u << 16); }
__device__ inline float bfhi(uint u) { return __uint_as_float(u & 0xffff0000u); }

// ---------------- K1 mega-kernel bodies ----------------

// swizzle [K,O] fp32 weight into MFMA B-frag order:
// Wz[((c*(O/16)+nb)*64 + lane)*8 + j] = W[c*32 + (lane>>4)*8 + j][nb*16 + (lane&15)]
__device__ inline void swz_body(const float* __restrict__ W, ushort* __restrict__ Wz,
                                int O, int t) {
    int lane = t & 63, cb = t >> 6;
    int NBm = O / 16;
    int c = cb / NBm, nb = cb % NBm;
    int quad = lane >> 4, l16 = lane & 15;
#pragma unroll
    for (int j = 0; j < 8; j++) {
        float v = W[(size_t)(c * 32 + quad * 8 + j) * O + nb * 16 + l16];
        Wz[(size_t)t * 8 + j] = f2bf(v);
    }
}

// GEMM1: x_p = relu(x @ Wp + bp); fp32 x, inline Wp swizzle (no deps in-dispatch)
__device__ void gemm1_body(int gb, const float* __restrict__ x,
                           const float* __restrict__ Wp, const float* __restrict__ bp,
                           ushort* __restrict__ feats, ushort* ldsA) {
    constexpr int LDA = 40;
    const int tid = threadIdx.x;
    const int wave = tid >> 6, lane = tid & 63;
    const int quad = lane >> 4, l16 = lane & 15;
    const int node0 = gb * 64;

    floatx4 acc[4];
#pragma unroll
    for (int nb = 0; nb < 4; nb++) acc[nb] = (floatx4){0.f, 0.f, 0.f, 0.f};

#pragma unroll
    for (int kk = 0; kk < 2; kk++) {
        const int k0 = kk * 32;
        __syncthreads();
        {
            int row = tid >> 2, seg = tid & 3;
            int node = node0 + row;
            float4 v0 = {0.f,0.f,0.f,0.f}, v1 = {0.f,0.f,0.f,0.f};
            if (node < N_NODES) {
                v0 = *(const float4*)&x[(size_t)node * 64 + k0 + seg * 8];
                v1 = *(const float4*)&x[(size_t)node * 64 + k0 + seg * 8 + 4];
            }
            ushort4 o0, o1;
            o0.x = f2bf(v0.x); o0.y = f2bf(v0.y); o0.z = f2bf(v0.z); o0.w = f2bf(v0.w);
            o1.x = f2bf(v1.x); o1.y = f2bf(v1.y); o1.z = f2bf(v1.z); o1.w = f2bf(v1.w);
            *(ushort4*)&ldsA[row * LDA + seg * 8] = o0;
            *(ushort4*)&ldsA[row * LDA + seg * 8 + 4] = o1;
        }
        __syncthreads();

        short8 a = *(const short8*)&ldsA[(wave * 16 + l16) * LDA + quad * 8];
#pragma unroll
        for (int nb = 0; nb < 4; nb++) {
            short8 bfrag;
#pragma unroll
            for (int j = 0; j < 8; j++)
                bfrag[j] = (short)f2bf(Wp[(size_t)(k0 + quad * 8 + j) * 64 + nb * 16 + l16]);
            acc[nb] = __builtin_amdgcn_mfma_f32_16x16x32_bf16(a, bfrag, acc[nb], 0, 0, 0);
        }
    }

#pragma unroll
    for (int nb = 0; nb < 4; nb++) {
        int ncol = nb * 16 + l16;
        float bv = bp[ncol];
#pragma unroll
        for (int r = 0; r < 4; r++) {
            int node = node0 + wave * 16 + quad * 4 + r;
            if (node >= N_NODES) continue;
            float v = fmaxf(acc[nb][r] + bv, 0.f);
            feats[(size_t)node * 256 + ncol] = f2bf(v);
        }
    }
}

// fused: [ELL fill | GEMM1 | x->bf16 convert | weight swizzles]
__global__ __launch_bounds__(256) void k1_mega(
    const int* __restrict__ src, const int* __restrict__ dst, int E,
    int* __restrict__ fillc, ushort* __restrict__ ell,
    const float* __restrict__ x, ushort* __restrict__ xb,
    const float* __restrict__ Wp, const float* __restrict__ bp, ushort* __restrict__ feats,
    const float* __restrict__ Wl1, ushort* __restrict__ zl1,
    const float* __restrict__ Wr1, ushort* __restrict__ zr1,
    const float* __restrict__ Wl2, ushort* __restrict__ zl2,
    const float* __restrict__ Wr2, ushort* __restrict__ zr2,
    const float* __restrict__ Wl3, ushort* __restrict__ zl3,
    const float* __restrict__ Wr3, ushort* __restrict__ zr3,
    int NF, int NG, int NC)
{
    __shared__ ushort ldsA[64 * 40];
    int b = blockIdx.x, tid = threadIdx.x;
    if (b < NF) {                       // ELL fill: 1 thread per edge (max TLP)
        int t = b * 256 + tid;
        if (t < E) {
            int d = dst[t], s = src[t];
            int p = atomicAdd(&fillc[d], 1);
            if (p < ELLW) ell[(size_t)d * ELLW + p] = (ushort)s;
        }
        return;
    }
    b -= NF;
    if (b < NG) { gemm1_body(b, x, Wp, bp, feats, ldsA); return; }
    b -= NG;
    if (b < NC) {                       // x -> bf16
        int t = b * 256 + tid;
        float4 v = ((const float4*)x)[t];
        ushort4 o;
        o.x = f2bf(v.x); o.y = f2bf(v.y); o.z = f2bf(v.z); o.w = f2bf(v.w);
        ((ushort4*)xb)[t] = o;
        return;
    }
    b -= NC;
    if      (b < 2)  swz_body(Wl1, zl1, 64,  (b - 0) * 256 + tid);
    else if (b < 4)  swz_body(Wr1, zr1, 64,  (b - 2) * 256 + tid);
    else if (b < 12) swz_body(Wl2, zl2, 128, (b - 4) * 256 + tid);
    else if (b < 20) swz_body(Wr2, zr2, 128, (b - 12) * 256 + tid);
    else if (b < 36) swz_body(Wl3, zl3, 128, (b - 20) * 256 + tid);
    else             swz_body(Wr3, zr3, 128, (b - 36) * 256 + tid);
}

// ---------------- gathers (mean, bf16, high-MLP edge split) ----------------
// One wave per node (max TLP). gather64: 8 lanes x 8 cols (uint4) x 8 edges
// in parallel, unroll-2 -> 16 edge-loads issued before one wait.
// gather128: 16 lanes x 8 cols x 4 edges, unroll-4 -> same property.

__global__ __launch_bounds__(256) void gather64_k(const int* __restrict__ fillc,
                                                  const ushort* __restrict__ ell,
                                                  const ushort* __restrict__ in, int sin,
                                                  ushort* __restrict__ out, int sout) {
    int node = blockIdx.x * 4 + (threadIdx.x >> 6);
    if (node >= N_NODES) return;
    int lane = threadIdx.x & 63;
    int sub = lane >> 3, c = lane & 7;       // edge slot sub, cols 8c..8c+7
    int n = fillc[node]; int nc = (n > ELLW) ? ELLW : n;
    const ushort* base = ell + (size_t)node * ELLW;
    float a[8];
#pragma unroll
    for (int j = 0; j < 8; j++) a[j] = 0.f;

    int i = sub;
    for (; i + 8 < nc; i += 16) {
        uint4 u0 = *(const uint4*)&in[(size_t)base[i] * sin + 8 * c];
        uint4 u1 = *(const uint4*)&in[(size_t)base[i + 8] * sin + 8 * c];
        a[0] += bflo(u0.x) + bflo(u1.x);  a[1] += bfhi(u0.x) + bfhi(u1.x);
        a[2] += bflo(u0.y) + bflo(u1.y);  a[3] += bfhi(u0.y) + bfhi(u1.y);
        a[4] += bflo(u0.z) + bflo(u1.z);  a[5] += bfhi(u0.z) + bfhi(u1.z);
        a[6] += bflo(u0.w) + bflo(u1.w);  a[7] += bfhi(u0.w) + bfhi(u1.w);
    }
    if (i < nc) {
        uint4 u0 = *(const uint4*)&in[(size_t)base[i] * sin + 8 * c];
        a[0] += bflo(u0.x);  a[1] += bfhi(u0.x);
        a[2] += bflo(u0.y);  a[3] += bfhi(u0.y);
        a[4] += bflo(u0.z);  a[5] += bfhi(u0.z);
        a[6] += bflo(u0.w);  a[7] += bfhi(u0.w);
    }
#pragma unroll
    for (int d = 8; d < 64; d <<= 1)
#pragma unroll
        for (int j = 0; j < 8; j++) a[j] += __shfl_xor(a[j], d);
    if (sub == 0) {
        float iv = 1.0f / fmaxf((float)n, 1.0f);
        uint4 r;
        r.x = (uint)f2bf(a[0] * iv) | ((uint)f2bf(a[1] * iv) << 16);
        r.y = (uint)f2bf(a[2] * iv) | ((uint)f2bf(a[3] * iv) << 16);
        r.z = (uint)f2bf(a[4] * iv) | ((uint)f2bf(a[5] * iv) << 16);
        r.w = (uint)f2bf(a[6] * iv) | ((uint)f2bf(a[7] * iv) << 16);
        *(uint4*)&out[(size_t)node * sout + 8 * c] = r;
    }
}

__global__ __launch_bounds__(256) void gather128_k(const int* __restrict__ fillc,
                                                   const ushort* __restrict__ ell,
                                                   const ushort* __restrict__ in, int sin,
                                                   ushort* __restrict__ out, int sout) {
    int node = blockIdx.x * 4 + (threadIdx.x >> 6);
    if (node >= N_NODES) return;
    int lane = threadIdx.x & 63;
    int sub = lane >> 4, c = lane & 15;      // edge slot sub, cols 8c..8c+7
    int n = fillc[node]; int nc = (n > ELLW) ? ELLW : n;
    const ushort* base = ell + (size_t)node * ELLW;
    float a[8];
#pragma unroll
    for (int j = 0; j < 8; j++) a[j] = 0.f;

    int i = sub;
    for (; i + 12 < nc; i += 16) {
        uint4 u0 = *(const uint4*)&in[(size_t)base[i] * sin + 8 * c];
        uint4 u1 = *(const uint4*)&in[(size_t)base[i + 4] * sin + 8 * c];
        uint4 u2 = *(const uint4*)&in[(size_t)base[i + 8] * sin + 8 * c];
        uint4 u3 = *(const uint4*)&in[(size_t)base[i + 12] * sin + 8 * c];
        a[0] += (bflo(u0.x) + bflo(u1.x)) + (bflo(u2.x) + bflo(u3.x));
        a[1] += (bfhi(u0.x) + bfhi(u1.x)) + (bfhi(u2.x) + bfhi(u3.x));
        a[2] += (bflo(u0.y) + bflo(u1.y)) + (bflo(u2.y) + bflo(u3.y));
        a[3] += (bfhi(u0.y) + bfhi(u1.y)) + (bfhi(u2.y) + bfhi(u3.y));
        a[4] += (bflo(u0.z) + bflo(u1.z)) + (bflo(u2.z) + bflo(u3.z));
        a[5] += (bfhi(u0.z) + bfhi(u1.z)) + (bfhi(u2.z) + bfhi(u3.z));
        a[6] += (bflo(u0.w) + bflo(u1.w)) + (bflo(u2.w) + bflo(u3.w));
        a[7] += (bfhi(u0.w) + bfhi(u1.w)) + (bfhi(u2.w) + bfhi(u3.w));
    }
    for (; i < nc; i += 4) {
        uint4 u0 = *(const uint4*)&in[(size_t)base[i] * sin + 8 * c];
        a[0] += bflo(u0.x);  a[1] += bfhi(u0.x);
        a[2] += bflo(u0.y);  a[3] += bfhi(u0.y);
        a[4] += bflo(u0.z);  a[5] += bfhi(u0.z);
        a[6] += bflo(u0.w);  a[7] += bfhi(u0.w);
    }
#pragma unroll
    for (int d = 16; d < 64; d <<= 1)
#pragma unroll
        for (int j = 0; j < 8; j++) a[j] += __shfl_xor(a[j], d);
    if (sub == 0) {
        float iv = 1.0f / fmaxf((float)n, 1.0f);
        uint4 r;
        r.x = (uint)f2bf(a[0] * iv) | ((uint)f2bf(a[1] * iv) << 16);
        r.y = (uint)f2bf(a[2] * iv) | ((uint)f2bf(a[3] * iv) << 16);
        r.z = (uint)f2bf(a[4] * iv) | ((uint)f2bf(a[5] * iv) << 16);
        r.w = (uint)f2bf(a[6] * iv) | ((uint)f2bf(a[7] * iv) << 16);
        *(uint4*)&out[(size_t)node * sout + 8 * c] = r;
    }
}

// ---------------- MFMA GEMM (layers 1/2/3) ----------------
// out[i, ocol+n] = relu( (A1[i,:K1] @ W1)[n] + (A2[i,:K2] @ W2)[n] + bias[n] )

template <int O, bool OUT_BF16>
__global__ __launch_bounds__(256) void mfma_gemm_k(
    const ushort* __restrict__ A1, int s1, int K1, const ushort* __restrict__ Wz1,
    const ushort* __restrict__ A2, int s2, int K2, const ushort* __restrict__ Wz2,
    const float* __restrict__ bias, void* __restrict__ outp, int so, int ocol)
{
    constexpr int NB = O / 16;
    constexpr int LDA = 40;
    __shared__ ushort ldsA[64 * LDA];

    const int tid = threadIdx.x;
    const int wave = tid >> 6, lane = tid & 63;
    const int quad = lane >> 4, l16 = lane & 15;
    const int node0 = blockIdx.x * 64;

    floatx4 acc[NB];
#pragma unroll
    for (int nb = 0; nb < NB; nb++) acc[nb] = (floatx4){0.f, 0.f, 0.f, 0.f};

#pragma unroll 1
    for (int phase = 0; phase < 2; ++phase) {
        const ushort* A = phase ? A2 : A1;
        const ushort* Wz = phase ? Wz2 : Wz1;
        const int K = phase ? K2 : K1;
        const int sA = phase ? s2 : s1;

#pragma unroll 1
        for (int k0 = 0; k0 < K; k0 += 32) {
            __syncthreads();
            {
                int row = tid >> 2, seg = tid & 3;
                int node = node0 + row;
                uint4 v = {0u, 0u, 0u, 0u};
                if (node < N_NODES)
                    v = *(const uint4*)&A[(size_t)node * sA + k0 + seg * 8];
                *(uint4*)&ldsA[row * LDA + seg * 8] = v;
            }
            __syncthreads();

            short8 a = *(const short8*)&ldsA[(wave * 16 + l16) * LDA + quad * 8];
            const short8* bz = (const short8*)Wz + (size_t)(k0 >> 5) * NB * 64;
#pragma unroll
            for (int nb = 0; nb < NB; nb++) {
                short8 b = bz[nb * 64 + lane];
                acc[nb] = __builtin_amdgcn_mfma_f32_16x16x32_bf16(a, b, acc[nb], 0, 0, 0);
            }
        }
    }

#pragma unroll
    for (int nb = 0; nb < NB; nb++) {
        int ncol = nb * 16 + l16;
        float bv = bias[ncol];
#pragma unroll
        for (int r = 0; r < 4; r++) {
            int node = node0 + wave * 16 + quad * 4 + r;
            if (node >= N_NODES) continue;
            float v = fmaxf(acc[nb][r] + bv, 0.f);
            if (OUT_BF16)
                ((ushort*)outp)[(size_t)node * so + ocol + ncol] = f2bf(v);
            else
                ((float*)outp)[(size_t)node * so + ocol + ncol] = v;
        }
    }
}

// ---------------- launch ----------------

extern "C" void kernel_launch(void* const* d_in, const int* in_sizes, int n_in,
                              void* d_out, int out_size, void* d_ws, size_t ws_size,
                              hipStream_t stream) {
    const float* x   = (const float*)d_in[0];
    const int*   ei  = (const int*)d_in[1];
    const float* Wp  = (const float*)d_in[2];
    const float* bp  = (const float*)d_in[3];
    const float* Wl1 = (const float*)d_in[4];
    const float* bl1 = (const float*)d_in[5];
    const float* Wr1 = (const float*)d_in[6];
    const float* Wl2 = (const float*)d_in[7];
    const float* bl2 = (const float*)d_in[8];
    const float* Wr2 = (const float*)d_in[9];
    const float* Wl3 = (const float*)d_in[10];
    const float* bl3 = (const float*)d_in[11];
    const float* Wr3 = (const float*)d_in[12];

    const int E = in_sizes[1] / 2;
    const int N = N_NODES;
    const int* src = ei;
    const int* dst = ei + E;

    // ---- workspace carve-up (all offsets 16B-aligned) ----
    char* p = (char*)d_ws;
    ushort* xb    = (ushort*)p;  p += (size_t)N * 64 * 2;
    ushort* feats = (ushort*)p;  p += (size_t)N * 256 * 2;
    ushort* aggx  = (ushort*)p;  p += (size_t)N * 64 * 2;
    ushort* aggf  = (ushort*)p;  p += (size_t)N * 256 * 2;
    int* fillc    = (int*)p;     p += (size_t)N * 4;
    ushort* ell   = (ushort*)p;  p += (size_t)N * ELLW * 2;
    ushort* zl1   = (ushort*)p;  p += 64 * 64 * 2;
    ushort* zr1   = (ushort*)p;  p += 64 * 64 * 2;
    ushort* zl2   = (ushort*)p;  p += 128 * 128 * 2;
    ushort* zr2   = (ushort*)p;  p += 128 * 128 * 2;
    ushort* zl3   = (ushort*)p;  p += 256 * 128 * 2;
    ushort* zr3   = (ushort*)p;  p += 256 * 128 * 2;

    hipMemsetAsync(fillc, 0, (size_t)N * sizeof(int), stream);

    const int NF = (E + 255) / 256;       // 3125 fill blocks
    const int NG = (N + 63) / 64;         // 782 gemm blocks
    const int NC = (N * 64 / 4) / 256;    // 3125 cvt blocks

    // K1: fill + GEMM1(x_p) + cvt + swz
    k1_mega<<<NF + NG + NC + 52, 256, 0, stream>>>(
        src, dst, E, fillc, ell, x, xb, Wp, bp, feats,
        Wl1, zl1, Wr1, zr1, Wl2, zl2, Wr2, zr2, Wl3, zl3, Wr3, zr3,
        NF, NG, NC);

    // aggx = mean-gather(xb)
    gather64_k<<<(N + 3) / 4, 256, 0, stream>>>(fillc, ell, xb, 64, aggx, 64);

    // h1 -> feats[:,64:128]
    mfma_gemm_k<64, true><<<NG, 256, 0, stream>>>(
        aggx, 64, 64, zl1, xb, 64, 64, zr1, bl1, feats, 256, 64);

    // aggf[:,0:128] = mean-gather(feats[:,0:128]) (layers 2 and 3)
    gather128_k<<<(N + 3) / 4, 256, 0, stream>>>(fillc, ell, feats, 256, aggf, 256);

    // h2 -> feats[:,128:256]
    mfma_gemm_k<128, true><<<NG, 256, 0, stream>>>(
        aggf, 256, 128, zl2, feats, 256, 128, zr2, bl2, feats, 256, 128);

    // aggf[:,128:256] = mean-gather(h2)
    gather128_k<<<(N + 3) / 4, 256, 0, stream>>>(fillc, ell, feats + 128, 256, aggf + 128, 256);

    // h3 -> d_out (fp32)
    mfma_gemm_k<128, false><<<NG, 256, 0, stream>>>(
        aggf, 256, 256, zl3, feats, 256, 256, zr3, bl3, (float*)d_out, 128, 0);
}